// Round 4
// baseline (911.746 us; speedup 1.0000x reference)
//
#include <hip/hip_runtime.h>
#include <math.h>

constexpr int N_NODES   = 500000;
constexpr int N_EDGES   = 16000000;
constexpr int BSHIFT    = 12;
constexpr int BSZ       = 1 << BSHIFT;                 // 4096 nodes / bucket
constexpr int NB        = (N_NODES + BSZ - 1) / BSZ;   // 123 buckets
constexpr int CHK       = 4096;                        // edges per sort chunk (32 KB LDS buf)
constexpr int NCHK      = (N_EDGES + CHK - 1) / CHK;   // 3907 chunks
constexpr int SPB_SHIFT = 4;
constexpr int SPB       = 1 << SPB_SHIFT;              // 16 consumer slices / bucket
constexpr int NSEG      = NB * NB;                     // 15129 (dstb,srcb) segments

// ---------------------------------------------------------------------------
// v11: two-level (dstb, srcb) sort. v8-v10 showed the gather kernels are
// pinned at ~0.25 lines/cy/CU regardless of per-thread MLP (2..6) => per-CU
// L1-miss-queue (MSHR ~64 @ ~250cy L2 latency) wall, not request-issue limit.
// Fix: make gathers LDS-local. Edges get sorted by (dst bucket, src bucket);
// consumers walk src-bucket segments, staging the 16KB y / 32KB g2 window
// into LDS per segment -> per-edge gather = ds_read, no L1/L2 misses.
//   s[k] = sum_e w*dis[d]*g2[s,k] + sum_v dv^2*h[v,k] + N*b2[k]
// ws layout (bytes):
//   [0)            A   : 16M uint2, dst-bucket sorted, pack=(dst_local<<19)|src
//   [128,000,000)  y   : N f32
//   [130,000,000)  dis : N f32
//   [132,000,000)  g2  : N float2 (dis*hW2)
//   [136,000,000)  meta: counts[NB*NCHK] bases[NB*NCHK] offsets1[NB+1]
//                        rowsum[NB] counts2[NB*NB*SPB] bases2[NB*NB*SPB]
//                        segbase[NB*NB+1] sacc[2]      (~5.9 MB)
// A2 (two-level sorted, 128 MB) = d_in[1] (edge_index, consumed by scatter1)
// deg/inagg staging (32.2 MB)   = d_in[2] (edge_weight, consumed by scatter1)
// harness restores d_in every call.
// ---------------------------------------------------------------------------

static __device__ __forceinline__ uint2 ntload2(const uint2* __restrict__ p) {
    unsigned long long v =
        __builtin_nontemporal_load((const unsigned long long*)p);
    uint2 r; r.x = (unsigned)v; r.y = (unsigned)(v >> 32);
    return r;
}

// per-chunk dst-bucket histogram (int4 reads; CHK divisible by 4)
__global__ __launch_bounds__(256) void k_count1(const int4* __restrict__ dst4,
                                                unsigned* __restrict__ counts) {
    __shared__ unsigned hist[NB];
    int c = blockIdx.x;
    for (int t = threadIdx.x; t < NB; t += 256) hist[t] = 0;
    __syncthreads();
    int lo4 = c * (CHK / 4);
    int hi4 = min(lo4 + CHK / 4, N_EDGES / 4);
    for (int q = lo4 + threadIdx.x; q < hi4; q += 256) {
        int4 d = dst4[q];
        atomicAdd(&hist[d.x >> BSHIFT], 1u);
        atomicAdd(&hist[d.y >> BSHIFT], 1u);
        atomicAdd(&hist[d.z >> BSHIFT], 1u);
        atomicAdd(&hist[d.w >> BSHIFT], 1u);
    }
    __syncthreads();
    for (int b = threadIdx.x; b < NB; b += 256)
        counts[(size_t)b * NCHK + c] = hist[b];
}

// per-bucket-row exclusive scan over chunks (coalesced), emits row totals
__global__ __launch_bounds__(256) void k_rowscan(const unsigned* __restrict__ counts,
                                                 unsigned* __restrict__ bases,
                                                 unsigned* __restrict__ rowsum) {
    __shared__ unsigned tile[256];
    __shared__ unsigned carry;
    int b = blockIdx.x;
    if (threadIdx.x == 0) carry = 0;
    __syncthreads();
    for (int t0 = 0; t0 < NCHK; t0 += 256) {
        int c = t0 + threadIdx.x;
        unsigned v = (c < NCHK) ? counts[(size_t)b * NCHK + c] : 0u;
        tile[threadIdx.x] = v;
        __syncthreads();
#pragma unroll
        for (int off = 1; off < 256; off <<= 1) {
            unsigned u = (threadIdx.x >= off) ? tile[threadIdx.x - off] : 0u;
            __syncthreads();
            tile[threadIdx.x] += u;
            __syncthreads();
        }
        unsigned excl = tile[threadIdx.x] - v;
        if (c < NCHK) bases[(size_t)b * NCHK + c] = carry + excl;
        __syncthreads();
        if (threadIdx.x == 0) carry += tile[255];
        __syncthreads();
    }
    if (threadIdx.x == 0) rowsum[b] = carry;
}

// exclusive scan over 123 row sums -> bucket offsets
__global__ __launch_bounds__(128) void k_bucketscan(const unsigned* __restrict__ rowsum,
                                                    unsigned* __restrict__ offsets1) {
    __shared__ unsigned tile[128];
    int t = threadIdx.x;
    unsigned v = (t < NB) ? rowsum[t] : 0u;
    tile[t] = v;
    __syncthreads();
#pragma unroll
    for (int off = 1; off < 128; off <<= 1) {
        unsigned u = (t >= off) ? tile[t - off] : 0u;
        __syncthreads();
        tile[t] += u;
        __syncthreads();
    }
    if (t < NB) offsets1[t] = tile[t] - v;
    if (t == 0) offsets1[NB] = tile[127];
}

// LDS chunk-sort scatter (level 1: by dst bucket); wave-per-bucket-run writeout
__global__ __launch_bounds__(256) void k_scatter1(const int4* __restrict__ src4,
                                                  const int4* __restrict__ dst4,
                                                  const float4* __restrict__ w4,
                                                  const unsigned* __restrict__ bases,
                                                  const unsigned* __restrict__ offsets1,
                                                  uint2* __restrict__ A) {
    __shared__ uint2    buf[CHK];
    __shared__ unsigned hist[NB];
    __shared__ unsigned coff[NB + 1];
    __shared__ unsigned cur[NB];
    __shared__ int      gbase[NB];
    __shared__ unsigned sc[128];
    int c = blockIdx.x;
    int lo4 = c * (CHK / 4);
    int hi4 = min(lo4 + CHK / 4, N_EDGES / 4);
    int n = (hi4 - lo4) * 4;
    for (int t = threadIdx.x; t < NB; t += 256) { hist[t] = 0; cur[t] = 0; }
    __syncthreads();
    for (int q = lo4 + threadIdx.x; q < hi4; q += 256) {
        int4 d = dst4[q];
        atomicAdd(&hist[d.x >> BSHIFT], 1u);
        atomicAdd(&hist[d.y >> BSHIFT], 1u);
        atomicAdd(&hist[d.z >> BSHIFT], 1u);
        atomicAdd(&hist[d.w >> BSHIFT], 1u);
    }
    __syncthreads();
    {   // exclusive scan of hist (NB entries padded to 128)
        int t = threadIdx.x;
        if (t < 128) sc[t] = (t < NB) ? hist[t] : 0u;
        __syncthreads();
#pragma unroll
        for (int off = 1; off < 128; off <<= 1) {
            unsigned u = 0;
            if (t < 128 && t >= off) u = sc[t - off];
            __syncthreads();
            if (t < 128) sc[t] += u;
            __syncthreads();
        }
        if (t < NB) coff[t] = sc[t] - hist[t];
        if (t == 0) coff[NB] = (unsigned)n;
        __syncthreads();
        if (t < NB)
            gbase[t] = (int)(offsets1[t] + bases[(size_t)t * NCHK + c]) - (int)coff[t];
    }
    __syncthreads();
    for (int q = lo4 + threadIdx.x; q < hi4; q += 256) {
        int4   s = src4[q];
        int4   d = dst4[q];
        float4 w = w4[q];
        {
            int b = d.x >> BSHIFT;
            unsigned p = coff[b] + atomicAdd(&cur[b], 1u);
            buf[p] = make_uint2(((unsigned)(d.x & (BSZ - 1)) << 19) | (unsigned)s.x,
                                __float_as_uint(w.x));
        }
        {
            int b = d.y >> BSHIFT;
            unsigned p = coff[b] + atomicAdd(&cur[b], 1u);
            buf[p] = make_uint2(((unsigned)(d.y & (BSZ - 1)) << 19) | (unsigned)s.y,
                                __float_as_uint(w.y));
        }
        {
            int b = d.z >> BSHIFT;
            unsigned p = coff[b] + atomicAdd(&cur[b], 1u);
            buf[p] = make_uint2(((unsigned)(d.z & (BSZ - 1)) << 19) | (unsigned)s.z,
                                __float_as_uint(w.z));
        }
        {
            int b = d.w >> BSHIFT;
            unsigned p = coff[b] + atomicAdd(&cur[b], 1u);
            buf[p] = make_uint2(((unsigned)(d.w & (BSZ - 1)) << 19) | (unsigned)s.w,
                                __float_as_uint(w.w));
        }
    }
    __syncthreads();
    int wave = threadIdx.x >> 6;
    int lane = threadIdx.x & 63;
    for (int b = wave; b < NB; b += 4) {
        int r0 = (int)coff[b], r1 = (int)coff[b + 1];
        int gb = gbase[b];
        for (int i = r0 + lane; i < r1; i += 64)
            A[gb + i] = buf[i];
    }
}

// slice [e0,e1) of bucket b for this block
__device__ __forceinline__ void slice_bounds(const unsigned* offsets1,
                                             int& b, int& e0, int& e1) {
    b = blockIdx.x >> SPB_SHIFT;
    int s = blockIdx.x & (SPB - 1);
    int base = (int)offsets1[b];
    int len  = (int)offsets1[b + 1] - base;
    e0 = base + (int)(((long long)len * s) >> SPB_SHIFT);
    e1 = base + (int)(((long long)len * (s + 1)) >> SPB_SHIFT);
}

// merged: deg bins (LDS) + per-slice srcb histogram for the level-2 sort
__global__ __launch_bounds__(256) void k_cd(const uint2* __restrict__ A,
                                            const unsigned* __restrict__ offsets1,
                                            unsigned* __restrict__ counts2,
                                            float* __restrict__ stagingD) {
    __shared__ float    bins[BSZ];
    __shared__ unsigned h[NB];
    int dstb, e0, e1;
    slice_bounds(offsets1, dstb, e0, e1);
    int s = blockIdx.x & (SPB - 1);
    for (int i = threadIdx.x; i < BSZ; i += 256) bins[i] = 0.0f;
    for (int i = threadIdx.x; i < NB; i += 256) h[i] = 0u;
    __syncthreads();
    for (int e = e0 + threadIdx.x; e < e1; e += 256) {
        uint2 a = ntload2(A + e);
        atomicAdd(&bins[a.x >> 19], __uint_as_float(a.y));
        atomicAdd(&h[(a.x >> 12) & 0x7F], 1u);
    }
    __syncthreads();
    float* out = stagingD + (size_t)blockIdx.x * BSZ;
    for (int i = threadIdx.x; i < BSZ; i += 256) out[i] = bins[i];
    for (int i = threadIdx.x; i < NB; i += 256)
        counts2[((size_t)dstb * NB + i) * SPB + s] = h[i];
}

// fold deg staging -> dis, y
__global__ __launch_bounds__(256) void k_dis(const float* __restrict__ staging,
                                             const float* __restrict__ x,
                                             float* __restrict__ dis,
                                             float* __restrict__ y) {
    int i = blockIdx.x * 256 + threadIdx.x;
    if (i >= N_NODES) return;
    int b = i >> BSHIFT, dl = i & (BSZ - 1);
    const float* st = staging + ((size_t)b << (BSHIFT + SPB_SHIFT)) + dl;
    float deg = 1.0f;  // self-loop
#pragma unroll
    for (int s = 0; s < SPB; ++s) deg += st[(size_t)s << BSHIFT];
    float d = rsqrtf(deg);
    dis[i] = d;
    y[i]   = d * x[i];
}

// per-dstb exclusive scan of counts2 (srcb-major, slice-inner) -> bases2 +
// segment starts segbase[dstb*NB+srcb]
__global__ __launch_bounds__(256) void k_scan2(const unsigned* __restrict__ counts2,
                                               const unsigned* __restrict__ offsets1,
                                               unsigned* __restrict__ bases2,
                                               unsigned* __restrict__ segbase) {
    __shared__ unsigned tile[256];
    __shared__ unsigned carry;
    int d = blockIdx.x;
    const int n = NB * SPB;  // 1968
    const unsigned* cin = counts2 + (size_t)d * n;
    unsigned* bout = bases2 + (size_t)d * n;
    unsigned off1 = offsets1[d];
    if (threadIdx.x == 0) carry = 0;
    __syncthreads();
    for (int t0 = 0; t0 < n; t0 += 256) {
        int i = t0 + threadIdx.x;
        unsigned v = (i < n) ? cin[i] : 0u;
        tile[threadIdx.x] = v;
        __syncthreads();
#pragma unroll
        for (int off = 1; off < 256; off <<= 1) {
            unsigned u = (threadIdx.x >= off) ? tile[threadIdx.x - off] : 0u;
            __syncthreads();
            tile[threadIdx.x] += u;
            __syncthreads();
        }
        if (i < n) {
            unsigned excl = carry + tile[threadIdx.x] - v;
            bout[i] = off1 + excl;
            if ((i & (SPB - 1)) == 0)
                segbase[d * NB + (i >> SPB_SHIFT)] = off1 + excl;
        }
        __syncthreads();
        if (threadIdx.x == 0) carry += tile[255];
        __syncthreads();
    }
    if (d == NB - 1 && threadIdx.x == 0) segbase[NSEG] = (unsigned)N_EDGES;
}

// level-2 scatter: within dst bucket, order by src bucket (LDS counters only)
__global__ __launch_bounds__(256) void k_scatter2(const uint2* __restrict__ A,
                                                  const unsigned* __restrict__ offsets1,
                                                  const unsigned* __restrict__ bases2,
                                                  uint2* __restrict__ A2) {
    __shared__ unsigned cur[NB];
    __shared__ unsigned base[NB];
    int dstb, e0, e1;
    slice_bounds(offsets1, dstb, e0, e1);
    int s = blockIdx.x & (SPB - 1);
    for (int i = threadIdx.x; i < NB; i += 256) {
        cur[i]  = 0u;
        base[i] = bases2[((size_t)dstb * NB + i) * SPB + s];
    }
    __syncthreads();
    for (int e = e0 + threadIdx.x; e < e1; e += 256) {
        uint2 a = ntload2(A + e);
        int srcb = (a.x >> 12) & 0x7F;
        unsigned p = base[srcb] + atomicAdd(&cur[srcb], 1u);
        A2[p] = a;
    }
}

// inagg: segment-walk, y window staged in LDS; gathers are ds_reads
__global__ __launch_bounds__(256) void k_in(const uint2* __restrict__ A2,
                                            const unsigned* __restrict__ segbase,
                                            const unsigned* __restrict__ offsets1,
                                            const float* __restrict__ y,
                                            float* __restrict__ staging) {
    __shared__ float bins[BSZ];   // 16 KB
    __shared__ float ytab[BSZ];   // 16 KB
    int dstb, e0, e1;
    slice_bounds(offsets1, dstb, e0, e1);
    for (int i = threadIdx.x; i < BSZ; i += 256) bins[i] = 0.0f;
    const unsigned* sb = segbase + (size_t)dstb * NB;   // sb[0..NB] valid
    int lo = 0, hi = NB - 1;
    while (lo < hi) { int mid = (lo + hi + 1) >> 1; if ((int)sb[mid] <= e0) lo = mid; else hi = mid - 1; }
    int srcb = lo;
    int e = e0;
    __syncthreads();
    while (e < e1) {
        int segend = (int)sb[srcb + 1];
        if (segend <= e) { ++srcb; continue; }
        int pe = min(segend, e1);
        const float4* ys = (const float4*)(y + (srcb << BSHIFT));
        float4* yt = (float4*)ytab;
        for (int i = threadIdx.x; i < BSZ / 4; i += 256) yt[i] = ys[i];
        __syncthreads();
        for (int ee = e + threadIdx.x; ee < pe; ee += 256) {
            uint2 a = ntload2(A2 + ee);
            atomicAdd(&bins[a.x >> 19],
                      __uint_as_float(a.y) * ytab[a.x & (BSZ - 1)]);
        }
        __syncthreads();
        e = pe;
        ++srcb;
    }
    float* out = staging + (size_t)blockIdx.x * BSZ;
    for (int i = threadIdx.x; i < BSZ; i += 256) out[i] = bins[i];
}

// fold inagg staging; per-node MLP; g2 = dis*hW2; self-loop term -> sacc
__global__ __launch_bounds__(256) void k_h(const float* __restrict__ staging,
                                           const float* __restrict__ dis,
                                           const float* __restrict__ x,
                                           const float* __restrict__ W1,
                                           const float* __restrict__ b1,
                                           const float* __restrict__ W2,
                                           float2* __restrict__ g2,
                                           float* __restrict__ sacc) {
    int i = blockIdx.x * 256 + threadIdx.x;
    float c0 = 0.0f, c1 = 0.0f;
    if (i < N_NODES) {
        int b = i >> BSHIFT, dl = i & (BSZ - 1);
        const float* st = staging + ((size_t)b << (BSHIFT + SPB_SHIFT)) + dl;
        float inagg = 0.0f;
#pragma unroll
        for (int s = 0; s < SPB; ++s) inagg += st[(size_t)s << BSHIFT];
        float dv   = dis[i];
        float agg1 = dv * (inagg + dv * x[i]);
        float h0 = 0.0f, h1 = 0.0f;
#pragma unroll
        for (int j = 0; j < 16; ++j) {
            float a = fmaxf(fmaf(agg1, W1[j], b1[j]), 0.0f);
            h0 = fmaf(a, W2[2 * j + 0], h0);
            h1 = fmaf(a, W2[2 * j + 1], h1);
        }
        g2[i] = make_float2(dv * h0, dv * h1);
        c0 = dv * dv * h0;
        c1 = dv * dv * h1;
    }
#pragma unroll
    for (int off = 32; off > 0; off >>= 1) {
        c0 += __shfl_down(c0, off, 64);
        c1 += __shfl_down(c1, off, 64);
    }
    __shared__ float red0[4], red1[4];
    int wave = threadIdx.x >> 6, lane = threadIdx.x & 63;
    if (lane == 0) { red0[wave] = c0; red1[wave] = c1; }
    __syncthreads();
    if (threadIdx.x == 0) {
        atomicAdd(&sacc[0], red0[0] + red0[1] + red0[2] + red0[3]);
        atomicAdd(&sacc[1], red1[0] + red1[1] + red1[2] + red1[3]);
    }
}

// edge reduction: segment-walk, g2 window staged in LDS; dis LDS-local
__global__ __launch_bounds__(256) void k_out(const uint2* __restrict__ A2,
                                             const unsigned* __restrict__ segbase,
                                             const unsigned* __restrict__ offsets1,
                                             const float* __restrict__ dis,
                                             const float2* __restrict__ g2,
                                             float* __restrict__ sacc) {
    __shared__ float  disL[BSZ];   // 16 KB
    __shared__ float2 gtab[BSZ];   // 32 KB
    int dstb, e0, e1;
    slice_bounds(offsets1, dstb, e0, e1);
    int nbase = dstb << BSHIFT;
    for (int i = threadIdx.x; i < BSZ; i += 256) {
        int node = nbase + i;
        disL[i] = (node < N_NODES) ? dis[node] : 0.0f;
    }
    const unsigned* sb = segbase + (size_t)dstb * NB;
    int lo = 0, hi = NB - 1;
    while (lo < hi) { int mid = (lo + hi + 1) >> 1; if ((int)sb[mid] <= e0) lo = mid; else hi = mid - 1; }
    int srcb = lo;
    int e = e0;
    float c0 = 0.0f, c1 = 0.0f;
    __syncthreads();
    while (e < e1) {
        int segend = (int)sb[srcb + 1];
        if (segend <= e) { ++srcb; continue; }
        int pe = min(segend, e1);
        const float4* gs = (const float4*)(g2 + (srcb << BSHIFT));
        float4* gt = (float4*)gtab;
        for (int i = threadIdx.x; i < BSZ / 2; i += 256) gt[i] = gs[i];
        __syncthreads();
        for (int ee = e + threadIdx.x; ee < pe; ee += 256) {
            uint2 a = ntload2(A2 + ee);
            float2 g = gtab[a.x & (BSZ - 1)];
            float wd = __uint_as_float(a.y) * disL[a.x >> 19];
            c0 = fmaf(wd, g.x, c0);
            c1 = fmaf(wd, g.y, c1);
        }
        __syncthreads();
        e = pe;
        ++srcb;
    }
#pragma unroll
    for (int off = 32; off > 0; off >>= 1) {
        c0 += __shfl_down(c0, off, 64);
        c1 += __shfl_down(c1, off, 64);
    }
    __shared__ float red0[4], red1[4];
    int wave = threadIdx.x >> 6, lane = threadIdx.x & 63;
    if (lane == 0) { red0[wave] = c0; red1[wave] = c1; }
    __syncthreads();
    if (threadIdx.x == 0) {
        atomicAdd(&sacc[0], red0[0] + red0[1] + red0[2] + red0[3]);
        atomicAdd(&sacc[1], red1[0] + red1[1] + red1[2] + red1[3]);
    }
}

__global__ void k_final(const float* __restrict__ sacc,
                        const float* __restrict__ b2,
                        float* __restrict__ out) {
    if (threadIdx.x == 0 && blockIdx.x == 0) {
        float s0 = sacc[0] + (float)N_NODES * b2[0];
        float s1 = sacc[1] + (float)N_NODES * b2[1];
        float m = fmaxf(s0, s1);
        float e0 = __expf(s0 - m);
        float e1 = __expf(s1 - m);
        float inv = 1.0f / (e0 + e1);
        out[0] = e0 * inv;
        out[1] = e1 * inv;
    }
}

// ---------------- fallback path (R1 structure, ~8 MB ws) ----------------

__global__ __launch_bounds__(256) void k_init_fb(float* __restrict__ deg,
                                                 float* __restrict__ inagg,
                                                 float* __restrict__ outco,
                                                 float* __restrict__ sacc) {
    int i = blockIdx.x * blockDim.x + threadIdx.x;
    if (i < N_NODES) { deg[i] = 1.0f; inagg[i] = 0.0f; outco[i] = 0.0f; }
    if (i < 2) sacc[i] = 0.0f;
}

__global__ __launch_bounds__(256) void k_deg_fb(const int4* __restrict__ dst4,
                                                const float4* __restrict__ w4,
                                                float* __restrict__ deg) {
    int i = blockIdx.x * blockDim.x + threadIdx.x;
    int4 d = dst4[i]; float4 w = w4[i];
    atomicAdd(&deg[d.x], w.x); atomicAdd(&deg[d.y], w.y);
    atomicAdd(&deg[d.z], w.z); atomicAdd(&deg[d.w], w.w);
}

__global__ __launch_bounds__(256) void k_dis_fb(float* __restrict__ degdis,
                                                const float* __restrict__ x,
                                                float* __restrict__ y) {
    int i = blockIdx.x * blockDim.x + threadIdx.x;
    if (i < N_NODES) { float d = rsqrtf(degdis[i]); degdis[i] = d; y[i] = d * x[i]; }
}

__global__ __launch_bounds__(256) void k_edge2_fb(const int4* __restrict__ src4,
                                                  const int4* __restrict__ dst4,
                                                  const float4* __restrict__ w4,
                                                  const float* __restrict__ dis,
                                                  const float* __restrict__ y,
                                                  float* __restrict__ inagg,
                                                  float* __restrict__ outco) {
    int i = blockIdx.x * blockDim.x + threadIdx.x;
    int4 s = src4[i]; int4 d = dst4[i]; float4 w = w4[i];
    atomicAdd(&inagg[d.x], w.x * y[s.x]); atomicAdd(&inagg[d.y], w.y * y[s.y]);
    atomicAdd(&inagg[d.z], w.z * y[s.z]); atomicAdd(&inagg[d.w], w.w * y[s.w]);
    atomicAdd(&outco[s.x], w.x * dis[d.x]); atomicAdd(&outco[s.y], w.y * dis[d.y]);
    atomicAdd(&outco[s.z], w.z * dis[d.z]); atomicAdd(&outco[s.w], w.w * dis[d.w]);
}

__global__ __launch_bounds__(256) void k_node_fb(const float* __restrict__ dis,
                                                 const float* __restrict__ x,
                                                 const float* __restrict__ inagg,
                                                 const float* __restrict__ outco,
                                                 const float* __restrict__ W1,
                                                 const float* __restrict__ b1,
                                                 const float* __restrict__ W2,
                                                 float* __restrict__ sacc) {
    int i = blockIdx.x * blockDim.x + threadIdx.x;
    float c0 = 0.0f, c1 = 0.0f;
    if (i < N_NODES) {
        float dv = dis[i];
        float agg1 = dv * (inagg[i] + dv * x[i]);
        float coef = dv * outco[i] + dv * dv;
        float h0 = 0.0f, h1 = 0.0f;
#pragma unroll
        for (int j = 0; j < 16; ++j) {
            float a = fmaxf(fmaf(agg1, W1[j], b1[j]), 0.0f);
            h0 = fmaf(a, W2[2 * j + 0], h0);
            h1 = fmaf(a, W2[2 * j + 1], h1);
        }
        c0 = coef * h0; c1 = coef * h1;
    }
#pragma unroll
    for (int off = 32; off > 0; off >>= 1) {
        c0 += __shfl_down(c0, off, 64);
        c1 += __shfl_down(c1, off, 64);
    }
    __shared__ float red0[4], red1[4];
    int wave = threadIdx.x >> 6, lane = threadIdx.x & 63;
    if (lane == 0) { red0[wave] = c0; red1[wave] = c1; }
    __syncthreads();
    if (threadIdx.x == 0) {
        atomicAdd(&sacc[0], red0[0] + red0[1] + red0[2] + red0[3]);
        atomicAdd(&sacc[1], red1[0] + red1[1] + red1[2] + red1[3]);
    }
}

extern "C" void kernel_launch(void* const* d_in, const int* in_sizes, int n_in,
                              void* d_out, int out_size, void* d_ws, size_t ws_size,
                              hipStream_t stream) {
    const float* x  = (const float*)d_in[0];
    int*         ei = (int*)d_in[1];            // [2,E] int32 (row0 src, row1 dst)
    float*       ew = (float*)d_in[2];
    const float* W1 = (const float*)d_in[3];
    const float* b1 = (const float*)d_in[4];
    const float* W2 = (const float*)d_in[5];
    const float* b2 = (const float*)d_in[6];
    float* out = (float*)d_out;

    const int* src = ei;
    const int* dst = ei + N_EDGES;

    const int TB = 256;
    const int nodeBlocks = (N_NODES + TB - 1) / TB;

    // fast-path layout in ws
    char* base = (char*)d_ws;
    uint2*    A   = (uint2*)base;
    float*    y   = (float*)(base + 128000000);
    float*    dis = (float*)(base + 130000000);
    float2*   g2  = (float2*)(base + 132000000);
    unsigned* counts   = (unsigned*)(base + 136000000);
    unsigned* bases    = counts + (size_t)NB * NCHK;
    unsigned* offsets1 = bases + (size_t)NB * NCHK;
    unsigned* rowsum   = offsets1 + (NB + 1);
    unsigned* counts2  = rowsum + NB;
    unsigned* bases2   = counts2 + (size_t)NB * NB * SPB;
    unsigned* segbase  = bases2 + (size_t)NB * NB * SPB;
    float*    sacc     = (float*)(segbase + NSEG + 1);
    const size_t fastNeed = (size_t)((char*)(sacc + 2) - base) + 64;

    if (ws_size >= fastNeed) {
        // A2 (level-2 sorted) reuses edge_index (128 MB, consumed by scatter1);
        // deg/inagg staging reuses edge_weight (64 MB, consumed by scatter1)
        uint2* A2      = (uint2*)ei;
        float* staging = ew;           // NB*SPB*BSZ*4 = 32.2 MB <= 64 MB

        hipMemsetAsync(sacc, 0, 2 * sizeof(float), stream);

        k_count1<<<NCHK, TB, 0, stream>>>((const int4*)dst, counts);
        k_rowscan<<<NB, TB, 0, stream>>>(counts, bases, rowsum);
        k_bucketscan<<<1, 128, 0, stream>>>(rowsum, offsets1);
        k_scatter1<<<NCHK, TB, 0, stream>>>((const int4*)src, (const int4*)dst,
                                            (const float4*)ew, bases, offsets1, A);
        k_cd<<<NB * SPB, TB, 0, stream>>>(A, offsets1, counts2, staging);
        k_dis<<<nodeBlocks, TB, 0, stream>>>(staging, x, dis, y);
        k_scan2<<<NB, TB, 0, stream>>>(counts2, offsets1, bases2, segbase);
        k_scatter2<<<NB * SPB, TB, 0, stream>>>(A, offsets1, bases2, A2);
        k_in<<<NB * SPB, TB, 0, stream>>>(A2, segbase, offsets1, y, staging);
        k_h<<<nodeBlocks, TB, 0, stream>>>(staging, dis, x, W1, b1, W2, g2, sacc);
        k_out<<<NB * SPB, TB, 0, stream>>>(A2, segbase, offsets1, dis, g2, sacc);
        k_final<<<1, 64, 0, stream>>>(sacc, b2, out);
    } else {
        float* ws     = (float*)d_ws;
        float* degdis = ws;
        float* yf     = ws + N_NODES;
        float* inaggf = ws + 2 * N_NODES;
        float* outcof = ws + 3 * N_NODES;
        float* saccf  = ws + 4 * N_NODES;
        const int edgeBlocks = (N_EDGES / 4) / TB;

        k_init_fb<<<nodeBlocks, TB, 0, stream>>>(degdis, inaggf, outcof, saccf);
        k_deg_fb<<<edgeBlocks, TB, 0, stream>>>((const int4*)dst, (const float4*)ew, degdis);
        k_dis_fb<<<nodeBlocks, TB, 0, stream>>>(degdis, x, yf);
        k_edge2_fb<<<edgeBlocks, TB, 0, stream>>>((const int4*)src, (const int4*)dst,
                                                  (const float4*)ew, degdis, yf, inaggf, outcof);
        k_node_fb<<<nodeBlocks, TB, 0, stream>>>(degdis, x, inaggf, outcof, W1, b1, W2, saccf);
        k_final<<<1, 64, 0, stream>>>(saccf, b2, out);
    }
}

// Round 6
// 851.286 us; speedup vs baseline: 1.0710x; 1.0710x over previous
//
#include <hip/hip_runtime.h>
#include <math.h>

constexpr int N_NODES   = 500000;
constexpr int N_EDGES   = 16000000;
constexpr int BSHIFT    = 12;
constexpr int BSZ       = 1 << BSHIFT;                 // 4096 nodes / bucket
constexpr int NB        = (N_NODES + BSZ - 1) / BSZ;   // 123 buckets
constexpr int CHK       = 4096;                        // edges per sort chunk (32 KB LDS buf)
constexpr int NCHK      = (N_EDGES + CHK - 1) / CHK;   // 3907 chunks
constexpr int SPB_SHIFT = 4;
constexpr int SPB       = 1 << SPB_SHIFT;              // 16 consumer slices / bucket
constexpr int NSEG      = NB * NB;                     // 15129 (dstb,srcb) segments

// ---------------------------------------------------------------------------
// v13 = v12 resubmitted verbatim (round 5 failed on container acquisition,
// not on the kernel: no compile diagnostic, no test output; kernel audit
// found uniform barriers, <=46KB LDS, in-bounds writes).
// v12: coalesced-run writeout in BOTH scatter kernels.
// v11 counters: k_scatter2 202us, WRITE_SIZE 303MB vs 128 ideal (2.4x partial-
// line amplification from per-edge scattered 8B stores), VALUBusy 1.4% =>
// store-transaction wall. k_scatter1 (never in top-5: table shows only the
// max kernel x5 iterations) has the same structure + double global read.
// Fix: chunk -> LDS raw buf + histogram, scan, perm[] index via LDS counters,
// then wave-per-bucket-run writeout (contiguous bursts; boundary lines
// coalesce in L2 across consecutive subchunks). scatter1 now reads
// src/dst/w exactly once.
//   s[k] = sum_e w*dis[d]*g2[s,k] + sum_v dv^2*h[v,k] + N*b2[k]
// ws layout (bytes):
//   [0)            A   : 16M uint2, dst-bucket sorted, pack=(dst_local<<19)|src
//   [128,000,000)  y   : N f32
//   [130,000,000)  dis : N f32
//   [132,000,000)  g2  : N float2 (dis*hW2)
//   [136,000,000)  meta: counts[NB*NCHK] bases[NB*NCHK] offsets1[NB+1]
//                        rowsum[NB] counts2[NB*NB*SPB] bases2[NB*NB*SPB]
//                        segbase[NB*NB+1] sacc[2]      (~5.9 MB)
// A2 (two-level sorted, 128 MB) = d_in[1] (edge_index, consumed by scatter1)
// deg/inagg staging (32.2 MB)   = d_in[2] (edge_weight, consumed by scatter1)
// harness restores d_in every call.
// ---------------------------------------------------------------------------

static __device__ __forceinline__ uint2 ntload2(const uint2* __restrict__ p) {
    unsigned long long v =
        __builtin_nontemporal_load((const unsigned long long*)p);
    uint2 r; r.x = (unsigned)v; r.y = (unsigned)(v >> 32);
    return r;
}

// per-chunk dst-bucket histogram (int4 reads; CHK divisible by 4)
__global__ __launch_bounds__(256) void k_count1(const int4* __restrict__ dst4,
                                                unsigned* __restrict__ counts) {
    __shared__ unsigned hist[NB];
    int c = blockIdx.x;
    for (int t = threadIdx.x; t < NB; t += 256) hist[t] = 0;
    __syncthreads();
    int lo4 = c * (CHK / 4);
    int hi4 = min(lo4 + CHK / 4, N_EDGES / 4);
    for (int q = lo4 + threadIdx.x; q < hi4; q += 256) {
        int4 d = dst4[q];
        atomicAdd(&hist[d.x >> BSHIFT], 1u);
        atomicAdd(&hist[d.y >> BSHIFT], 1u);
        atomicAdd(&hist[d.z >> BSHIFT], 1u);
        atomicAdd(&hist[d.w >> BSHIFT], 1u);
    }
    __syncthreads();
    for (int b = threadIdx.x; b < NB; b += 256)
        counts[(size_t)b * NCHK + c] = hist[b];
}

// per-bucket-row exclusive scan over chunks (coalesced), emits row totals
__global__ __launch_bounds__(256) void k_rowscan(const unsigned* __restrict__ counts,
                                                 unsigned* __restrict__ bases,
                                                 unsigned* __restrict__ rowsum) {
    __shared__ unsigned tile[256];
    __shared__ unsigned carry;
    int b = blockIdx.x;
    if (threadIdx.x == 0) carry = 0;
    __syncthreads();
    for (int t0 = 0; t0 < NCHK; t0 += 256) {
        int c = t0 + threadIdx.x;
        unsigned v = (c < NCHK) ? counts[(size_t)b * NCHK + c] : 0u;
        tile[threadIdx.x] = v;
        __syncthreads();
#pragma unroll
        for (int off = 1; off < 256; off <<= 1) {
            unsigned u = (threadIdx.x >= off) ? tile[threadIdx.x - off] : 0u;
            __syncthreads();
            tile[threadIdx.x] += u;
            __syncthreads();
        }
        unsigned excl = tile[threadIdx.x] - v;
        if (c < NCHK) bases[(size_t)b * NCHK + c] = carry + excl;
        __syncthreads();
        if (threadIdx.x == 0) carry += tile[255];
        __syncthreads();
    }
    if (threadIdx.x == 0) rowsum[b] = carry;
}

// exclusive scan over 123 row sums -> bucket offsets
__global__ __launch_bounds__(128) void k_bucketscan(const unsigned* __restrict__ rowsum,
                                                    unsigned* __restrict__ offsets1) {
    __shared__ unsigned tile[128];
    int t = threadIdx.x;
    unsigned v = (t < NB) ? rowsum[t] : 0u;
    tile[t] = v;
    __syncthreads();
#pragma unroll
    for (int off = 1; off < 128; off <<= 1) {
        unsigned u = (t >= off) ? tile[t - off] : 0u;
        __syncthreads();
        tile[t] += u;
        __syncthreads();
    }
    if (t < NB) offsets1[t] = tile[t] - v;
    if (t == 0) offsets1[NB] = tile[127];
}

// level-1 scatter: single global read, LDS perm, coalesced run writeout
__global__ __launch_bounds__(256) void k_scatter1(const int4* __restrict__ src4,
                                                  const int4* __restrict__ dst4,
                                                  const float4* __restrict__ w4,
                                                  const unsigned* __restrict__ bases,
                                                  const unsigned* __restrict__ offsets1,
                                                  uint2* __restrict__ A) {
    __shared__ uint2          buf[CHK];    // 32 KB raw packed edges
    __shared__ unsigned short perm[CHK];   // 8 KB
    __shared__ unsigned char  dbb[CHK];    // 4 KB dstb per edge
    __shared__ unsigned hist[NB];
    __shared__ unsigned coff[NB + 1];
    __shared__ unsigned cur[NB];
    __shared__ unsigned goff[NB];
    __shared__ unsigned sc[128];
    int c = blockIdx.x;
    int lo4 = c * (CHK / 4);
    int hi4 = min(lo4 + CHK / 4, N_EDGES / 4);
    int n = (hi4 - lo4) * 4;
    for (int t = threadIdx.x; t < NB; t += 256) { hist[t] = 0; cur[t] = 0; }
    __syncthreads();
    for (int q = lo4 + threadIdx.x; q < hi4; q += 256) {
        int4   s = src4[q];
        int4   d = dst4[q];
        float4 w = w4[q];
        int i = (q - lo4) << 2;
        int bx = d.x >> BSHIFT, by = d.y >> BSHIFT;
        int bz = d.z >> BSHIFT, bw = d.w >> BSHIFT;
        buf[i + 0] = make_uint2(((unsigned)(d.x & (BSZ - 1)) << 19) | (unsigned)s.x,
                                __float_as_uint(w.x));
        buf[i + 1] = make_uint2(((unsigned)(d.y & (BSZ - 1)) << 19) | (unsigned)s.y,
                                __float_as_uint(w.y));
        buf[i + 2] = make_uint2(((unsigned)(d.z & (BSZ - 1)) << 19) | (unsigned)s.z,
                                __float_as_uint(w.z));
        buf[i + 3] = make_uint2(((unsigned)(d.w & (BSZ - 1)) << 19) | (unsigned)s.w,
                                __float_as_uint(w.w));
        dbb[i + 0] = (unsigned char)bx;
        dbb[i + 1] = (unsigned char)by;
        dbb[i + 2] = (unsigned char)bz;
        dbb[i + 3] = (unsigned char)bw;
        atomicAdd(&hist[bx], 1u);
        atomicAdd(&hist[by], 1u);
        atomicAdd(&hist[bz], 1u);
        atomicAdd(&hist[bw], 1u);
    }
    __syncthreads();
    {   // exclusive scan of hist (NB entries padded to 128)
        int t = threadIdx.x;
        if (t < 128) sc[t] = (t < NB) ? hist[t] : 0u;
        __syncthreads();
#pragma unroll
        for (int off = 1; off < 128; off <<= 1) {
            unsigned u = 0;
            if (t < 128 && t >= off) u = sc[t - off];
            __syncthreads();
            if (t < 128) sc[t] += u;
            __syncthreads();
        }
        if (t < NB) {
            coff[t] = sc[t] - hist[t];
            goff[t] = offsets1[t] + bases[(size_t)t * NCHK + c];
        }
        if (t == 0) coff[NB] = (unsigned)n;
    }
    __syncthreads();
    for (int i = threadIdx.x; i < n; i += 256) {
        int b = dbb[i];
        unsigned p = coff[b] + atomicAdd(&cur[b], 1u);
        perm[p] = (unsigned short)i;
    }
    __syncthreads();
    int wave = threadIdx.x >> 6;
    int lane = threadIdx.x & 63;
    for (int b = wave; b < NB; b += 4) {
        int r0 = (int)coff[b], r1 = (int)coff[b + 1];
        unsigned gb = goff[b];
        for (int i = r0 + lane; i < r1; i += 64)
            A[gb + (i - r0)] = buf[perm[i]];
    }
}

// slice [e0,e1) of bucket b for this block
__device__ __forceinline__ void slice_bounds(const unsigned* offsets1,
                                             int& b, int& e0, int& e1) {
    b = blockIdx.x >> SPB_SHIFT;
    int s = blockIdx.x & (SPB - 1);
    int base = (int)offsets1[b];
    int len  = (int)offsets1[b + 1] - base;
    e0 = base + (int)(((long long)len * s) >> SPB_SHIFT);
    e1 = base + (int)(((long long)len * (s + 1)) >> SPB_SHIFT);
}

// merged: deg bins (LDS) + per-slice srcb histogram for the level-2 sort
__global__ __launch_bounds__(256) void k_cd(const uint2* __restrict__ A,
                                            const unsigned* __restrict__ offsets1,
                                            unsigned* __restrict__ counts2,
                                            float* __restrict__ stagingD) {
    __shared__ float    bins[BSZ];
    __shared__ unsigned h[NB];
    int dstb, e0, e1;
    slice_bounds(offsets1, dstb, e0, e1);
    int s = blockIdx.x & (SPB - 1);
    for (int i = threadIdx.x; i < BSZ; i += 256) bins[i] = 0.0f;
    for (int i = threadIdx.x; i < NB; i += 256) h[i] = 0u;
    __syncthreads();
    for (int e = e0 + threadIdx.x; e < e1; e += 256) {
        uint2 a = ntload2(A + e);
        atomicAdd(&bins[a.x >> 19], __uint_as_float(a.y));
        atomicAdd(&h[(a.x >> 12) & 0x7F], 1u);
    }
    __syncthreads();
    float* out = stagingD + (size_t)blockIdx.x * BSZ;
    for (int i = threadIdx.x; i < BSZ; i += 256) out[i] = bins[i];
    for (int i = threadIdx.x; i < NB; i += 256)
        counts2[((size_t)dstb * NB + i) * SPB + s] = h[i];
}

// fold deg staging -> dis, y
__global__ __launch_bounds__(256) void k_dis(const float* __restrict__ staging,
                                             const float* __restrict__ x,
                                             float* __restrict__ dis,
                                             float* __restrict__ y) {
    int i = blockIdx.x * 256 + threadIdx.x;
    if (i >= N_NODES) return;
    int b = i >> BSHIFT, dl = i & (BSZ - 1);
    const float* st = staging + ((size_t)b << (BSHIFT + SPB_SHIFT)) + dl;
    float deg = 1.0f;  // self-loop
#pragma unroll
    for (int s = 0; s < SPB; ++s) deg += st[(size_t)s << BSHIFT];
    float d = rsqrtf(deg);
    dis[i] = d;
    y[i]   = d * x[i];
}

// per-dstb exclusive scan of counts2 (srcb-major, slice-inner) -> bases2 +
// segment starts segbase[dstb*NB+srcb]
__global__ __launch_bounds__(256) void k_scan2(const unsigned* __restrict__ counts2,
                                               const unsigned* __restrict__ offsets1,
                                               unsigned* __restrict__ bases2,
                                               unsigned* __restrict__ segbase) {
    __shared__ unsigned tile[256];
    __shared__ unsigned carry;
    int d = blockIdx.x;
    const int n = NB * SPB;  // 1968
    const unsigned* cin = counts2 + (size_t)d * n;
    unsigned* bout = bases2 + (size_t)d * n;
    unsigned off1 = offsets1[d];
    if (threadIdx.x == 0) carry = 0;
    __syncthreads();
    for (int t0 = 0; t0 < n; t0 += 256) {
        int i = t0 + threadIdx.x;
        unsigned v = (i < n) ? cin[i] : 0u;
        tile[threadIdx.x] = v;
        __syncthreads();
#pragma unroll
        for (int off = 1; off < 256; off <<= 1) {
            unsigned u = (threadIdx.x >= off) ? tile[threadIdx.x - off] : 0u;
            __syncthreads();
            tile[threadIdx.x] += u;
            __syncthreads();
        }
        if (i < n) {
            unsigned excl = carry + tile[threadIdx.x] - v;
            bout[i] = off1 + excl;
            if ((i & (SPB - 1)) == 0)
                segbase[d * NB + (i >> SPB_SHIFT)] = off1 + excl;
        }
        __syncthreads();
        if (threadIdx.x == 0) carry += tile[255];
        __syncthreads();
    }
    if (d == NB - 1 && threadIdx.x == 0) segbase[NSEG] = (unsigned)N_EDGES;
}

// level-2 scatter: LDS chunk-sort by srcb + coalesced run writeout
__global__ __launch_bounds__(256) void k_scatter2(const uint2* __restrict__ A,
                                                  const unsigned* __restrict__ offsets1,
                                                  const unsigned* __restrict__ bases2,
                                                  uint2* __restrict__ A2) {
    __shared__ uint2          buf[CHK];    // 32 KB
    __shared__ unsigned short perm[CHK];   // 8 KB
    __shared__ unsigned h[NB];
    __shared__ unsigned coff[NB + 1];
    __shared__ unsigned cur[NB];
    __shared__ unsigned wbase[NB];
    __shared__ unsigned sc[128];
    int dstb, e0, e1;
    slice_bounds(offsets1, dstb, e0, e1);
    int s = blockIdx.x & (SPB - 1);
    for (int i = threadIdx.x; i < NB; i += 256)
        wbase[i] = bases2[((size_t)dstb * NB + i) * SPB + s];
    for (int sub = e0; sub < e1; sub += CHK) {
        int n = min(CHK, e1 - sub);
        for (int i = threadIdx.x; i < NB; i += 256) { h[i] = 0u; cur[i] = 0u; }
        __syncthreads();
        for (int i = threadIdx.x; i < n; i += 256) {
            uint2 a = ntload2(A + sub + i);
            buf[i] = a;
            atomicAdd(&h[(a.x >> 12) & 0x7F], 1u);
        }
        __syncthreads();
        {   // exclusive scan
            int t = threadIdx.x;
            if (t < 128) sc[t] = (t < NB) ? h[t] : 0u;
            __syncthreads();
#pragma unroll
            for (int off = 1; off < 128; off <<= 1) {
                unsigned u = 0;
                if (t < 128 && t >= off) u = sc[t - off];
                __syncthreads();
                if (t < 128) sc[t] += u;
                __syncthreads();
            }
            if (t < NB) coff[t] = sc[t] - h[t];
            if (t == 0) coff[NB] = (unsigned)n;
        }
        __syncthreads();
        for (int i = threadIdx.x; i < n; i += 256) {
            int b = (buf[i].x >> 12) & 0x7F;
            unsigned p = coff[b] + atomicAdd(&cur[b], 1u);
            perm[p] = (unsigned short)i;
        }
        __syncthreads();
        int wave = threadIdx.x >> 6;
        int lane = threadIdx.x & 63;
        for (int b = wave; b < NB; b += 4) {
            int r0 = (int)coff[b], r1 = (int)coff[b + 1];
            unsigned gb = wbase[b];
            for (int i = r0 + lane; i < r1; i += 64)
                A2[gb + (i - r0)] = buf[perm[i]];
        }
        __syncthreads();
        for (int i = threadIdx.x; i < NB; i += 256) wbase[i] += h[i];
        __syncthreads();
    }
}

// inagg: segment-walk, y window staged in LDS; gathers are ds_reads
__global__ __launch_bounds__(256) void k_in(const uint2* __restrict__ A2,
                                            const unsigned* __restrict__ segbase,
                                            const unsigned* __restrict__ offsets1,
                                            const float* __restrict__ y,
                                            float* __restrict__ staging) {
    __shared__ float bins[BSZ];   // 16 KB
    __shared__ float ytab[BSZ];   // 16 KB
    int dstb, e0, e1;
    slice_bounds(offsets1, dstb, e0, e1);
    for (int i = threadIdx.x; i < BSZ; i += 256) bins[i] = 0.0f;
    const unsigned* sb = segbase + (size_t)dstb * NB;   // sb[0..NB] valid
    int lo = 0, hi = NB - 1;
    while (lo < hi) { int mid = (lo + hi + 1) >> 1; if ((int)sb[mid] <= e0) lo = mid; else hi = mid - 1; }
    int srcb = lo;
    int e = e0;
    __syncthreads();
    while (e < e1) {
        int segend = (int)sb[srcb + 1];
        if (segend <= e) { ++srcb; continue; }
        int pe = min(segend, e1);
        const float4* ys = (const float4*)(y + (srcb << BSHIFT));
        float4* yt = (float4*)ytab;
        for (int i = threadIdx.x; i < BSZ / 4; i += 256) yt[i] = ys[i];
        __syncthreads();
        for (int ee = e + threadIdx.x; ee < pe; ee += 256) {
            uint2 a = ntload2(A2 + ee);
            atomicAdd(&bins[a.x >> 19],
                      __uint_as_float(a.y) * ytab[a.x & (BSZ - 1)]);
        }
        __syncthreads();
        e = pe;
        ++srcb;
    }
    float* out = staging + (size_t)blockIdx.x * BSZ;
    for (int i = threadIdx.x; i < BSZ; i += 256) out[i] = bins[i];
}

// fold inagg staging; per-node MLP; g2 = dis*hW2; self-loop term -> sacc
__global__ __launch_bounds__(256) void k_h(const float* __restrict__ staging,
                                           const float* __restrict__ dis,
                                           const float* __restrict__ x,
                                           const float* __restrict__ W1,
                                           const float* __restrict__ b1,
                                           const float* __restrict__ W2,
                                           float2* __restrict__ g2,
                                           float* __restrict__ sacc) {
    int i = blockIdx.x * 256 + threadIdx.x;
    float c0 = 0.0f, c1 = 0.0f;
    if (i < N_NODES) {
        int b = i >> BSHIFT, dl = i & (BSZ - 1);
        const float* st = staging + ((size_t)b << (BSHIFT + SPB_SHIFT)) + dl;
        float inagg = 0.0f;
#pragma unroll
        for (int s = 0; s < SPB; ++s) inagg += st[(size_t)s << BSHIFT];
        float dv   = dis[i];
        float agg1 = dv * (inagg + dv * x[i]);
        float h0 = 0.0f, h1 = 0.0f;
#pragma unroll
        for (int j = 0; j < 16; ++j) {
            float a = fmaxf(fmaf(agg1, W1[j], b1[j]), 0.0f);
            h0 = fmaf(a, W2[2 * j + 0], h0);
            h1 = fmaf(a, W2[2 * j + 1], h1);
        }
        g2[i] = make_float2(dv * h0, dv * h1);
        c0 = dv * dv * h0;
        c1 = dv * dv * h1;
    }
#pragma unroll
    for (int off = 32; off > 0; off >>= 1) {
        c0 += __shfl_down(c0, off, 64);
        c1 += __shfl_down(c1, off, 64);
    }
    __shared__ float red0[4], red1[4];
    int wave = threadIdx.x >> 6, lane = threadIdx.x & 63;
    if (lane == 0) { red0[wave] = c0; red1[wave] = c1; }
    __syncthreads();
    if (threadIdx.x == 0) {
        atomicAdd(&sacc[0], red0[0] + red0[1] + red0[2] + red0[3]);
        atomicAdd(&sacc[1], red1[0] + red1[1] + red1[2] + red1[3]);
    }
}

// edge reduction: segment-walk, g2 window staged in LDS; dis LDS-local
__global__ __launch_bounds__(256) void k_out(const uint2* __restrict__ A2,
                                             const unsigned* __restrict__ segbase,
                                             const unsigned* __restrict__ offsets1,
                                             const float* __restrict__ dis,
                                             const float2* __restrict__ g2,
                                             float* __restrict__ sacc) {
    __shared__ float  disL[BSZ];   // 16 KB
    __shared__ float2 gtab[BSZ];   // 32 KB
    int dstb, e0, e1;
    slice_bounds(offsets1, dstb, e0, e1);
    int nbase = dstb << BSHIFT;
    for (int i = threadIdx.x; i < BSZ; i += 256) {
        int node = nbase + i;
        disL[i] = (node < N_NODES) ? dis[node] : 0.0f;
    }
    const unsigned* sb = segbase + (size_t)dstb * NB;
    int lo = 0, hi = NB - 1;
    while (lo < hi) { int mid = (lo + hi + 1) >> 1; if ((int)sb[mid] <= e0) lo = mid; else hi = mid - 1; }
    int srcb = lo;
    int e = e0;
    float c0 = 0.0f, c1 = 0.0f;
    __syncthreads();
    while (e < e1) {
        int segend = (int)sb[srcb + 1];
        if (segend <= e) { ++srcb; continue; }
        int pe = min(segend, e1);
        const float4* gs = (const float4*)(g2 + (srcb << BSHIFT));
        float4* gt = (float4*)gtab;
        for (int i = threadIdx.x; i < BSZ / 2; i += 256) gt[i] = gs[i];
        __syncthreads();
        for (int ee = e + threadIdx.x; ee < pe; ee += 256) {
            uint2 a = ntload2(A2 + ee);
            float2 g = gtab[a.x & (BSZ - 1)];
            float wd = __uint_as_float(a.y) * disL[a.x >> 19];
            c0 = fmaf(wd, g.x, c0);
            c1 = fmaf(wd, g.y, c1);
        }
        __syncthreads();
        e = pe;
        ++srcb;
    }
#pragma unroll
    for (int off = 32; off > 0; off >>= 1) {
        c0 += __shfl_down(c0, off, 64);
        c1 += __shfl_down(c1, off, 64);
    }
    __shared__ float red0[4], red1[4];
    int wave = threadIdx.x >> 6, lane = threadIdx.x & 63;
    if (lane == 0) { red0[wave] = c0; red1[wave] = c1; }
    __syncthreads();
    if (threadIdx.x == 0) {
        atomicAdd(&sacc[0], red0[0] + red0[1] + red0[2] + red0[3]);
        atomicAdd(&sacc[1], red1[0] + red1[1] + red1[2] + red1[3]);
    }
}

__global__ void k_final(const float* __restrict__ sacc,
                        const float* __restrict__ b2,
                        float* __restrict__ out) {
    if (threadIdx.x == 0 && blockIdx.x == 0) {
        float s0 = sacc[0] + (float)N_NODES * b2[0];
        float s1 = sacc[1] + (float)N_NODES * b2[1];
        float m = fmaxf(s0, s1);
        float e0 = __expf(s0 - m);
        float e1 = __expf(s1 - m);
        float inv = 1.0f / (e0 + e1);
        out[0] = e0 * inv;
        out[1] = e1 * inv;
    }
}

// ---------------- fallback path (R1 structure, ~8 MB ws) ----------------

__global__ __launch_bounds__(256) void k_init_fb(float* __restrict__ deg,
                                                 float* __restrict__ inagg,
                                                 float* __restrict__ outco,
                                                 float* __restrict__ sacc) {
    int i = blockIdx.x * blockDim.x + threadIdx.x;
    if (i < N_NODES) { deg[i] = 1.0f; inagg[i] = 0.0f; outco[i] = 0.0f; }
    if (i < 2) sacc[i] = 0.0f;
}

__global__ __launch_bounds__(256) void k_deg_fb(const int4* __restrict__ dst4,
                                                const float4* __restrict__ w4,
                                                float* __restrict__ deg) {
    int i = blockIdx.x * blockDim.x + threadIdx.x;
    int4 d = dst4[i]; float4 w = w4[i];
    atomicAdd(&deg[d.x], w.x); atomicAdd(&deg[d.y], w.y);
    atomicAdd(&deg[d.z], w.z); atomicAdd(&deg[d.w], w.w);
}

__global__ __launch_bounds__(256) void k_dis_fb(float* __restrict__ degdis,
                                                const float* __restrict__ x,
                                                float* __restrict__ y) {
    int i = blockIdx.x * blockDim.x + threadIdx.x;
    if (i < N_NODES) { float d = rsqrtf(degdis[i]); degdis[i] = d; y[i] = d * x[i]; }
}

__global__ __launch_bounds__(256) void k_edge2_fb(const int4* __restrict__ src4,
                                                  const int4* __restrict__ dst4,
                                                  const float4* __restrict__ w4,
                                                  const float* __restrict__ dis,
                                                  const float* __restrict__ y,
                                                  float* __restrict__ inagg,
                                                  float* __restrict__ outco) {
    int i = blockIdx.x * blockDim.x + threadIdx.x;
    int4 s = src4[i]; int4 d = dst4[i]; float4 w = w4[i];
    atomicAdd(&inagg[d.x], w.x * y[s.x]); atomicAdd(&inagg[d.y], w.y * y[s.y]);
    atomicAdd(&inagg[d.z], w.z * y[s.z]); atomicAdd(&inagg[d.w], w.w * y[s.w]);
    atomicAdd(&outco[s.x], w.x * dis[d.x]); atomicAdd(&outco[s.y], w.y * dis[d.y]);
    atomicAdd(&outco[s.z], w.z * dis[d.z]); atomicAdd(&outco[s.w], w.w * dis[d.w]);
}

__global__ __launch_bounds__(256) void k_node_fb(const float* __restrict__ dis,
                                                 const float* __restrict__ x,
                                                 const float* __restrict__ inagg,
                                                 const float* __restrict__ outco,
                                                 const float* __restrict__ W1,
                                                 const float* __restrict__ b1,
                                                 const float* __restrict__ W2,
                                                 float* __restrict__ sacc) {
    int i = blockIdx.x * blockDim.x + threadIdx.x;
    float c0 = 0.0f, c1 = 0.0f;
    if (i < N_NODES) {
        float dv = dis[i];
        float agg1 = dv * (inagg[i] + dv * x[i]);
        float coef = dv * outco[i] + dv * dv;
        float h0 = 0.0f, h1 = 0.0f;
#pragma unroll
        for (int j = 0; j < 16; ++j) {
            float a = fmaxf(fmaf(agg1, W1[j], b1[j]), 0.0f);
            h0 = fmaf(a, W2[2 * j + 0], h0);
            h1 = fmaf(a, W2[2 * j + 1], h1);
        }
        c0 = coef * h0; c1 = coef * h1;
    }
#pragma unroll
    for (int off = 32; off > 0; off >>= 1) {
        c0 += __shfl_down(c0, off, 64);
        c1 += __shfl_down(c1, off, 64);
    }
    __shared__ float red0[4], red1[4];
    int wave = threadIdx.x >> 6, lane = threadIdx.x & 63;
    if (lane == 0) { red0[wave] = c0; red1[wave] = c1; }
    __syncthreads();
    if (threadIdx.x == 0) {
        atomicAdd(&sacc[0], red0[0] + red0[1] + red0[2] + red0[3]);
        atomicAdd(&sacc[1], red1[0] + red1[1] + red1[2] + red1[3]);
    }
}

extern "C" void kernel_launch(void* const* d_in, const int* in_sizes, int n_in,
                              void* d_out, int out_size, void* d_ws, size_t ws_size,
                              hipStream_t stream) {
    const float* x  = (const float*)d_in[0];
    int*         ei = (int*)d_in[1];            // [2,E] int32 (row0 src, row1 dst)
    float*       ew = (float*)d_in[2];
    const float* W1 = (const float*)d_in[3];
    const float* b1 = (const float*)d_in[4];
    const float* W2 = (const float*)d_in[5];
    const float* b2 = (const float*)d_in[6];
    float* out = (float*)d_out;

    const int* src = ei;
    const int* dst = ei + N_EDGES;

    const int TB = 256;
    const int nodeBlocks = (N_NODES + TB - 1) / TB;

    // fast-path layout in ws
    char* base = (char*)d_ws;
    uint2*    A   = (uint2*)base;
    float*    y   = (float*)(base + 128000000);
    float*    dis = (float*)(base + 130000000);
    float2*   g2  = (float2*)(base + 132000000);
    unsigned* counts   = (unsigned*)(base + 136000000);
    unsigned* bases    = counts + (size_t)NB * NCHK;
    unsigned* offsets1 = bases + (size_t)NB * NCHK;
    unsigned* rowsum   = offsets1 + (NB + 1);
    unsigned* counts2  = rowsum + NB;
    unsigned* bases2   = counts2 + (size_t)NB * NB * SPB;
    unsigned* segbase  = bases2 + (size_t)NB * NB * SPB;
    float*    sacc     = (float*)(segbase + NSEG + 1);
    const size_t fastNeed = (size_t)((char*)(sacc + 2) - base) + 64;

    if (ws_size >= fastNeed) {
        // A2 (level-2 sorted) reuses edge_index (128 MB, consumed by scatter1);
        // deg/inagg staging reuses edge_weight (64 MB, consumed by scatter1)
        uint2* A2      = (uint2*)ei;
        float* staging = ew;           // NB*SPB*BSZ*4 = 32.2 MB <= 64 MB

        hipMemsetAsync(sacc, 0, 2 * sizeof(float), stream);

        k_count1<<<NCHK, TB, 0, stream>>>((const int4*)dst, counts);
        k_rowscan<<<NB, TB, 0, stream>>>(counts, bases, rowsum);
        k_bucketscan<<<1, 128, 0, stream>>>(rowsum, offsets1);
        k_scatter1<<<NCHK, TB, 0, stream>>>((const int4*)src, (const int4*)dst,
                                            (const float4*)ew, bases, offsets1, A);
        k_cd<<<NB * SPB, TB, 0, stream>>>(A, offsets1, counts2, staging);
        k_dis<<<nodeBlocks, TB, 0, stream>>>(staging, x, dis, y);
        k_scan2<<<NB, TB, 0, stream>>>(counts2, offsets1, bases2, segbase);
        k_scatter2<<<NB * SPB, TB, 0, stream>>>(A, offsets1, bases2, A2);
        k_in<<<NB * SPB, TB, 0, stream>>>(A2, segbase, offsets1, y, staging);
        k_h<<<nodeBlocks, TB, 0, stream>>>(staging, dis, x, W1, b1, W2, g2, sacc);
        k_out<<<NB * SPB, TB, 0, stream>>>(A2, segbase, offsets1, dis, g2, sacc);
        k_final<<<1, 64, 0, stream>>>(sacc, b2, out);
    } else {
        float* ws     = (float*)d_ws;
        float* degdis = ws;
        float* yf     = ws + N_NODES;
        float* inaggf = ws + 2 * N_NODES;
        float* outcof = ws + 3 * N_NODES;
        float* saccf  = ws + 4 * N_NODES;
        const int edgeBlocks = (N_EDGES / 4) / TB;

        k_init_fb<<<nodeBlocks, TB, 0, stream>>>(degdis, inaggf, outcof, saccf);
        k_deg_fb<<<edgeBlocks, TB, 0, stream>>>((const int4*)dst, (const float4*)ew, degdis);
        k_dis_fb<<<nodeBlocks, TB, 0, stream>>>(degdis, x, yf);
        k_edge2_fb<<<edgeBlocks, TB, 0, stream>>>((const int4*)src, (const int4*)dst,
                                                  (const float4*)ew, degdis, yf, inaggf, outcof);
        k_node_fb<<<nodeBlocks, TB, 0, stream>>>(degdis, x, inaggf, outcof, W1, b1, W2, saccf);
        k_final<<<1, 64, 0, stream>>>(saccf, b2, out);
    }
}

// Round 7
// 815.976 us; speedup vs baseline: 1.1174x; 1.0433x over previous
//
#include <hip/hip_runtime.h>
#include <math.h>

constexpr int N_NODES   = 500000;
constexpr int N_EDGES   = 16000000;
constexpr int BSHIFT    = 12;
constexpr int BSZ       = 1 << BSHIFT;                 // 4096 nodes / bucket
constexpr int NB        = (N_NODES + BSZ - 1) / BSZ;   // 123 buckets
constexpr int CHK       = 4096;                        // edges per sort chunk (32 KB LDS buf)
constexpr int NCHK      = (N_EDGES + CHK - 1) / CHK;   // 3907 chunks
constexpr int SPB_SHIFT = 4;
constexpr int SPB       = 1 << SPB_SHIFT;              // 16 consumer slices / bucket
constexpr int NSEG      = NB * NB;                     // 15129 (dstb,srcb) segments

// ---------------------------------------------------------------------------
// v14: restructure consumers around dis-absorbed weights.
// v13 post-mortem: k_out 138us at 26% occupancy (49.6KB LDS) — per-segment
// 32KB gtab staging + 2 barriers amortized over only ~1060 edges. Fix:
//  (1) k_scatter2 absorbs dis[dst] into w (dis known by then; 16KB L1-hot
//      window): A2.y = w*dis[dst]. Then inagg' = dv*inagg (k_h: agg1 =
//      inagg' + dv^2*x) and the layer-2 edge term = sum w'*g2[src] — k_out
//      needs NO dst info.
//  (2) k_out goes srcb-major: block=(srcb, dstb-range); stage gtab ONCE per
//      block (amortized over ~8K edges via segbase runs), no inner barriers,
//      33KB LDS.
//  (3) k_in drops y-staging: srcb-sorted order makes y a rolling 16KB window
//      that L1 (32KB) catches; bins-only LDS, no segment walk.
//   s[k] = sum_e w'*g2[s,k] + sum_v dv^2*h[v,k] + N*b2[k]
// ws layout (bytes):
//   [0)            A   : 16M uint2, dst-bucket sorted, pack=(dst_local<<19)|src
//   [128,000,000)  y   : N f32
//   [130,000,000)  dis : N f32
//   [132,000,000)  g2  : N float2 (dis*hW2)
//   [136,000,000)  meta: counts[NB*NCHK] bases[NB*NCHK] offsets1[NB+1]
//                        rowsum[NB] counts2[NB*NB*SPB] bases2[NB*NB*SPB]
//                        segbase[NB*NB+1] sacc[2]      (~5.9 MB)
// A2 (two-level sorted, 128 MB) = d_in[1] (edge_index, consumed by scatter1)
// deg/inagg staging (32.2 MB)   = d_in[2] (edge_weight, consumed by scatter1)
// harness restores d_in every call.
// ---------------------------------------------------------------------------

static __device__ __forceinline__ uint2 ntload2(const uint2* __restrict__ p) {
    unsigned long long v =
        __builtin_nontemporal_load((const unsigned long long*)p);
    uint2 r; r.x = (unsigned)v; r.y = (unsigned)(v >> 32);
    return r;
}

// per-chunk dst-bucket histogram (int4 reads; CHK divisible by 4)
__global__ __launch_bounds__(256) void k_count1(const int4* __restrict__ dst4,
                                                unsigned* __restrict__ counts) {
    __shared__ unsigned hist[NB];
    int c = blockIdx.x;
    for (int t = threadIdx.x; t < NB; t += 256) hist[t] = 0;
    __syncthreads();
    int lo4 = c * (CHK / 4);
    int hi4 = min(lo4 + CHK / 4, N_EDGES / 4);
    for (int q = lo4 + threadIdx.x; q < hi4; q += 256) {
        int4 d = dst4[q];
        atomicAdd(&hist[d.x >> BSHIFT], 1u);
        atomicAdd(&hist[d.y >> BSHIFT], 1u);
        atomicAdd(&hist[d.z >> BSHIFT], 1u);
        atomicAdd(&hist[d.w >> BSHIFT], 1u);
    }
    __syncthreads();
    for (int b = threadIdx.x; b < NB; b += 256)
        counts[(size_t)b * NCHK + c] = hist[b];
}

// per-bucket-row exclusive scan over chunks (coalesced), emits row totals
__global__ __launch_bounds__(256) void k_rowscan(const unsigned* __restrict__ counts,
                                                 unsigned* __restrict__ bases,
                                                 unsigned* __restrict__ rowsum) {
    __shared__ unsigned tile[256];
    __shared__ unsigned carry;
    int b = blockIdx.x;
    if (threadIdx.x == 0) carry = 0;
    __syncthreads();
    for (int t0 = 0; t0 < NCHK; t0 += 256) {
        int c = t0 + threadIdx.x;
        unsigned v = (c < NCHK) ? counts[(size_t)b * NCHK + c] : 0u;
        tile[threadIdx.x] = v;
        __syncthreads();
#pragma unroll
        for (int off = 1; off < 256; off <<= 1) {
            unsigned u = (threadIdx.x >= off) ? tile[threadIdx.x - off] : 0u;
            __syncthreads();
            tile[threadIdx.x] += u;
            __syncthreads();
        }
        unsigned excl = tile[threadIdx.x] - v;
        if (c < NCHK) bases[(size_t)b * NCHK + c] = carry + excl;
        __syncthreads();
        if (threadIdx.x == 0) carry += tile[255];
        __syncthreads();
    }
    if (threadIdx.x == 0) rowsum[b] = carry;
}

// exclusive scan over 123 row sums -> bucket offsets
__global__ __launch_bounds__(128) void k_bucketscan(const unsigned* __restrict__ rowsum,
                                                    unsigned* __restrict__ offsets1) {
    __shared__ unsigned tile[128];
    int t = threadIdx.x;
    unsigned v = (t < NB) ? rowsum[t] : 0u;
    tile[t] = v;
    __syncthreads();
#pragma unroll
    for (int off = 1; off < 128; off <<= 1) {
        unsigned u = (t >= off) ? tile[t - off] : 0u;
        __syncthreads();
        tile[t] += u;
        __syncthreads();
    }
    if (t < NB) offsets1[t] = tile[t] - v;
    if (t == 0) offsets1[NB] = tile[127];
}

// level-1 scatter: single global read, LDS perm, coalesced run writeout
__global__ __launch_bounds__(256) void k_scatter1(const int4* __restrict__ src4,
                                                  const int4* __restrict__ dst4,
                                                  const float4* __restrict__ w4,
                                                  const unsigned* __restrict__ bases,
                                                  const unsigned* __restrict__ offsets1,
                                                  uint2* __restrict__ A) {
    __shared__ uint2          buf[CHK];    // 32 KB raw packed edges
    __shared__ unsigned short perm[CHK];   // 8 KB
    __shared__ unsigned char  dbb[CHK];    // 4 KB dstb per edge
    __shared__ unsigned hist[NB];
    __shared__ unsigned coff[NB + 1];
    __shared__ unsigned cur[NB];
    __shared__ unsigned goff[NB];
    __shared__ unsigned sc[128];
    int c = blockIdx.x;
    int lo4 = c * (CHK / 4);
    int hi4 = min(lo4 + CHK / 4, N_EDGES / 4);
    int n = (hi4 - lo4) * 4;
    for (int t = threadIdx.x; t < NB; t += 256) { hist[t] = 0; cur[t] = 0; }
    __syncthreads();
    for (int q = lo4 + threadIdx.x; q < hi4; q += 256) {
        int4   s = src4[q];
        int4   d = dst4[q];
        float4 w = w4[q];
        int i = (q - lo4) << 2;
        int bx = d.x >> BSHIFT, by = d.y >> BSHIFT;
        int bz = d.z >> BSHIFT, bw = d.w >> BSHIFT;
        buf[i + 0] = make_uint2(((unsigned)(d.x & (BSZ - 1)) << 19) | (unsigned)s.x,
                                __float_as_uint(w.x));
        buf[i + 1] = make_uint2(((unsigned)(d.y & (BSZ - 1)) << 19) | (unsigned)s.y,
                                __float_as_uint(w.y));
        buf[i + 2] = make_uint2(((unsigned)(d.z & (BSZ - 1)) << 19) | (unsigned)s.z,
                                __float_as_uint(w.z));
        buf[i + 3] = make_uint2(((unsigned)(d.w & (BSZ - 1)) << 19) | (unsigned)s.w,
                                __float_as_uint(w.w));
        dbb[i + 0] = (unsigned char)bx;
        dbb[i + 1] = (unsigned char)by;
        dbb[i + 2] = (unsigned char)bz;
        dbb[i + 3] = (unsigned char)bw;
        atomicAdd(&hist[bx], 1u);
        atomicAdd(&hist[by], 1u);
        atomicAdd(&hist[bz], 1u);
        atomicAdd(&hist[bw], 1u);
    }
    __syncthreads();
    {   // exclusive scan of hist (NB entries padded to 128)
        int t = threadIdx.x;
        if (t < 128) sc[t] = (t < NB) ? hist[t] : 0u;
        __syncthreads();
#pragma unroll
        for (int off = 1; off < 128; off <<= 1) {
            unsigned u = 0;
            if (t < 128 && t >= off) u = sc[t - off];
            __syncthreads();
            if (t < 128) sc[t] += u;
            __syncthreads();
        }
        if (t < NB) {
            coff[t] = sc[t] - hist[t];
            goff[t] = offsets1[t] + bases[(size_t)t * NCHK + c];
        }
        if (t == 0) coff[NB] = (unsigned)n;
    }
    __syncthreads();
    for (int i = threadIdx.x; i < n; i += 256) {
        int b = dbb[i];
        unsigned p = coff[b] + atomicAdd(&cur[b], 1u);
        perm[p] = (unsigned short)i;
    }
    __syncthreads();
    int wave = threadIdx.x >> 6;
    int lane = threadIdx.x & 63;
    for (int b = wave; b < NB; b += 4) {
        int r0 = (int)coff[b], r1 = (int)coff[b + 1];
        unsigned gb = goff[b];
        for (int i = r0 + lane; i < r1; i += 64)
            A[gb + (i - r0)] = buf[perm[i]];
    }
}

// slice [e0,e1) of bucket b for this block
__device__ __forceinline__ void slice_bounds(const unsigned* offsets1,
                                             int& b, int& e0, int& e1) {
    b = blockIdx.x >> SPB_SHIFT;
    int s = blockIdx.x & (SPB - 1);
    int base = (int)offsets1[b];
    int len  = (int)offsets1[b + 1] - base;
    e0 = base + (int)(((long long)len * s) >> SPB_SHIFT);
    e1 = base + (int)(((long long)len * (s + 1)) >> SPB_SHIFT);
}

// merged: deg bins (LDS) + per-slice srcb histogram for the level-2 sort
__global__ __launch_bounds__(256) void k_cd(const uint2* __restrict__ A,
                                            const unsigned* __restrict__ offsets1,
                                            unsigned* __restrict__ counts2,
                                            float* __restrict__ stagingD) {
    __shared__ float    bins[BSZ];
    __shared__ unsigned h[NB];
    int dstb, e0, e1;
    slice_bounds(offsets1, dstb, e0, e1);
    int s = blockIdx.x & (SPB - 1);
    for (int i = threadIdx.x; i < BSZ; i += 256) bins[i] = 0.0f;
    for (int i = threadIdx.x; i < NB; i += 256) h[i] = 0u;
    __syncthreads();
    for (int e = e0 + threadIdx.x; e < e1; e += 256) {
        uint2 a = ntload2(A + e);
        atomicAdd(&bins[a.x >> 19], __uint_as_float(a.y));
        atomicAdd(&h[(a.x >> 12) & 0x7F], 1u);
    }
    __syncthreads();
    float* out = stagingD + (size_t)blockIdx.x * BSZ;
    for (int i = threadIdx.x; i < BSZ; i += 256) out[i] = bins[i];
    for (int i = threadIdx.x; i < NB; i += 256)
        counts2[((size_t)dstb * NB + i) * SPB + s] = h[i];
}

// fold deg staging -> dis, y
__global__ __launch_bounds__(256) void k_dis(const float* __restrict__ staging,
                                             const float* __restrict__ x,
                                             float* __restrict__ dis,
                                             float* __restrict__ y) {
    int i = blockIdx.x * 256 + threadIdx.x;
    if (i >= N_NODES) return;
    int b = i >> BSHIFT, dl = i & (BSZ - 1);
    const float* st = staging + ((size_t)b << (BSHIFT + SPB_SHIFT)) + dl;
    float deg = 1.0f;  // self-loop
#pragma unroll
    for (int s = 0; s < SPB; ++s) deg += st[(size_t)s << BSHIFT];
    float d = rsqrtf(deg);
    dis[i] = d;
    y[i]   = d * x[i];
}

// per-dstb exclusive scan of counts2 (srcb-major, slice-inner) -> bases2 +
// segment starts segbase[dstb*NB+srcb]
__global__ __launch_bounds__(256) void k_scan2(const unsigned* __restrict__ counts2,
                                               const unsigned* __restrict__ offsets1,
                                               unsigned* __restrict__ bases2,
                                               unsigned* __restrict__ segbase) {
    __shared__ unsigned tile[256];
    __shared__ unsigned carry;
    int d = blockIdx.x;
    const int n = NB * SPB;  // 1968
    const unsigned* cin = counts2 + (size_t)d * n;
    unsigned* bout = bases2 + (size_t)d * n;
    unsigned off1 = offsets1[d];
    if (threadIdx.x == 0) carry = 0;
    __syncthreads();
    for (int t0 = 0; t0 < n; t0 += 256) {
        int i = t0 + threadIdx.x;
        unsigned v = (i < n) ? cin[i] : 0u;
        tile[threadIdx.x] = v;
        __syncthreads();
#pragma unroll
        for (int off = 1; off < 256; off <<= 1) {
            unsigned u = (threadIdx.x >= off) ? tile[threadIdx.x - off] : 0u;
            __syncthreads();
            tile[threadIdx.x] += u;
            __syncthreads();
        }
        if (i < n) {
            unsigned excl = carry + tile[threadIdx.x] - v;
            bout[i] = off1 + excl;
            if ((i & (SPB - 1)) == 0)
                segbase[d * NB + (i >> SPB_SHIFT)] = off1 + excl;
        }
        __syncthreads();
        if (threadIdx.x == 0) carry += tile[255];
        __syncthreads();
    }
    if (d == NB - 1 && threadIdx.x == 0) segbase[NSEG] = (unsigned)N_EDGES;
}

// level-2 scatter: LDS chunk-sort by srcb + coalesced run writeout.
// Absorbs dis[dst] into the weight: A2.y = w * dis[dst] (16KB L1-hot window).
__global__ __launch_bounds__(256) void k_scatter2(const uint2* __restrict__ A,
                                                  const unsigned* __restrict__ offsets1,
                                                  const unsigned* __restrict__ bases2,
                                                  const float* __restrict__ dis,
                                                  uint2* __restrict__ A2) {
    __shared__ uint2          buf[CHK];    // 32 KB
    __shared__ unsigned short perm[CHK];   // 8 KB
    __shared__ unsigned h[NB];
    __shared__ unsigned coff[NB + 1];
    __shared__ unsigned cur[NB];
    __shared__ unsigned wbase[NB];
    __shared__ unsigned sc[128];
    int dstb, e0, e1;
    slice_bounds(offsets1, dstb, e0, e1);
    int s = blockIdx.x & (SPB - 1);
    int nbase = dstb << BSHIFT;
    for (int i = threadIdx.x; i < NB; i += 256)
        wbase[i] = bases2[((size_t)dstb * NB + i) * SPB + s];
    for (int sub = e0; sub < e1; sub += CHK) {
        int n = min(CHK, e1 - sub);
        for (int i = threadIdx.x; i < NB; i += 256) { h[i] = 0u; cur[i] = 0u; }
        __syncthreads();
        for (int i = threadIdx.x; i < n; i += 256) {
            uint2 a = ntload2(A + sub + i);
            float wd = __uint_as_float(a.y) * dis[nbase + (int)(a.x >> 19)];
            buf[i] = make_uint2(a.x, __float_as_uint(wd));
            atomicAdd(&h[(a.x >> 12) & 0x7F], 1u);
        }
        __syncthreads();
        {   // exclusive scan
            int t = threadIdx.x;
            if (t < 128) sc[t] = (t < NB) ? h[t] : 0u;
            __syncthreads();
#pragma unroll
            for (int off = 1; off < 128; off <<= 1) {
                unsigned u = 0;
                if (t < 128 && t >= off) u = sc[t - off];
                __syncthreads();
                if (t < 128) sc[t] += u;
                __syncthreads();
            }
            if (t < NB) coff[t] = sc[t] - h[t];
            if (t == 0) coff[NB] = (unsigned)n;
        }
        __syncthreads();
        for (int i = threadIdx.x; i < n; i += 256) {
            int b = (buf[i].x >> 12) & 0x7F;
            unsigned p = coff[b] + atomicAdd(&cur[b], 1u);
            perm[p] = (unsigned short)i;
        }
        __syncthreads();
        int wave = threadIdx.x >> 6;
        int lane = threadIdx.x & 63;
        for (int b = wave; b < NB; b += 4) {
            int r0 = (int)coff[b], r1 = (int)coff[b + 1];
            unsigned gb = wbase[b];
            for (int i = r0 + lane; i < r1; i += 64)
                A2[gb + (i - r0)] = buf[perm[i]];
        }
        __syncthreads();
        for (int i = threadIdx.x; i < NB; i += 256) wbase[i] += h[i];
        __syncthreads();
    }
}

// inagg' = sum w'*y[src]: direct gather — srcb-sorted order makes y a rolling
// 16KB window, L1-resident. Bins-only LDS; no inner barriers.
__global__ __launch_bounds__(256) void k_in(const uint2* __restrict__ A2,
                                            const unsigned* __restrict__ offsets1,
                                            const float* __restrict__ y,
                                            float* __restrict__ staging) {
    __shared__ float bins[BSZ];   // 16 KB
    int dstb, e0, e1;
    slice_bounds(offsets1, dstb, e0, e1);
    for (int i = threadIdx.x; i < BSZ; i += 256) bins[i] = 0.0f;
    __syncthreads();
    for (int e = e0 + threadIdx.x; e < e1; e += 256) {
        uint2 a = ntload2(A2 + e);
        atomicAdd(&bins[a.x >> 19],
                  __uint_as_float(a.y) * y[a.x & 0x7FFFFu]);
    }
    __syncthreads();
    float* out = staging + (size_t)blockIdx.x * BSZ;
    for (int i = threadIdx.x; i < BSZ; i += 256) out[i] = bins[i];
}

// fold inagg' staging; per-node MLP; g2 = dis*hW2; self-loop term -> sacc
// (inagg' already includes dis[dst]: agg1 = inagg' + dv^2*x)
__global__ __launch_bounds__(256) void k_h(const float* __restrict__ staging,
                                           const float* __restrict__ dis,
                                           const float* __restrict__ x,
                                           const float* __restrict__ W1,
                                           const float* __restrict__ b1,
                                           const float* __restrict__ W2,
                                           float2* __restrict__ g2,
                                           float* __restrict__ sacc) {
    int i = blockIdx.x * 256 + threadIdx.x;
    float c0 = 0.0f, c1 = 0.0f;
    if (i < N_NODES) {
        int b = i >> BSHIFT, dl = i & (BSZ - 1);
        const float* st = staging + ((size_t)b << (BSHIFT + SPB_SHIFT)) + dl;
        float inagg = 0.0f;
#pragma unroll
        for (int s = 0; s < SPB; ++s) inagg += st[(size_t)s << BSHIFT];
        float dv   = dis[i];
        float agg1 = inagg + dv * dv * x[i];
        float h0 = 0.0f, h1 = 0.0f;
#pragma unroll
        for (int j = 0; j < 16; ++j) {
            float a = fmaxf(fmaf(agg1, W1[j], b1[j]), 0.0f);
            h0 = fmaf(a, W2[2 * j + 0], h0);
            h1 = fmaf(a, W2[2 * j + 1], h1);
        }
        g2[i] = make_float2(dv * h0, dv * h1);
        c0 = dv * dv * h0;
        c1 = dv * dv * h1;
    }
#pragma unroll
    for (int off = 32; off > 0; off >>= 1) {
        c0 += __shfl_down(c0, off, 64);
        c1 += __shfl_down(c1, off, 64);
    }
    __shared__ float red0[4], red1[4];
    int wave = threadIdx.x >> 6, lane = threadIdx.x & 63;
    if (lane == 0) { red0[wave] = c0; red1[wave] = c1; }
    __syncthreads();
    if (threadIdx.x == 0) {
        atomicAdd(&sacc[0], red0[0] + red0[1] + red0[2] + red0[3]);
        atomicAdd(&sacc[1], red1[0] + red1[1] + red1[2] + red1[3]);
    }
}

// edge reduction: srcb-major. Block=(srcb, dstb-range); stage gtab ONCE,
// walk per-dstb runs of this srcb via segbase. sum w'*g2[src]. No inner
// barriers; 33KB LDS.
__global__ __launch_bounds__(256) void k_out(const uint2* __restrict__ A2,
                                             const unsigned* __restrict__ segbase,
                                             const float2* __restrict__ g2,
                                             float* __restrict__ sacc) {
    __shared__ float2 gtab[BSZ];   // 32 KB
    int srcb = blockIdx.x >> SPB_SHIFT;
    int s    = blockIdx.x & (SPB - 1);
    int d0 = (NB * s) >> SPB_SHIFT;
    int d1 = (NB * (s + 1)) >> SPB_SHIFT;
    const float4* gs = (const float4*)(g2 + (srcb << BSHIFT));
    float4* gt = (float4*)gtab;
    for (int i = threadIdx.x; i < BSZ / 2; i += 256) gt[i] = gs[i];
    __syncthreads();
    float c0 = 0.0f, c1 = 0.0f;
    for (int dstb = d0; dstb < d1; ++dstb) {
        int r0 = (int)segbase[dstb * NB + srcb];
        int r1 = (int)segbase[dstb * NB + srcb + 1];
        for (int e = r0 + threadIdx.x; e < r1; e += 256) {
            uint2 a = ntload2(A2 + e);
            float2 g = gtab[a.x & (BSZ - 1)];
            float wd = __uint_as_float(a.y);
            c0 = fmaf(wd, g.x, c0);
            c1 = fmaf(wd, g.y, c1);
        }
    }
#pragma unroll
    for (int off = 32; off > 0; off >>= 1) {
        c0 += __shfl_down(c0, off, 64);
        c1 += __shfl_down(c1, off, 64);
    }
    __shared__ float red0[4], red1[4];
    int wave = threadIdx.x >> 6, lane = threadIdx.x & 63;
    if (lane == 0) { red0[wave] = c0; red1[wave] = c1; }
    __syncthreads();
    if (threadIdx.x == 0) {
        atomicAdd(&sacc[0], red0[0] + red0[1] + red0[2] + red0[3]);
        atomicAdd(&sacc[1], red1[0] + red1[1] + red1[2] + red1[3]);
    }
}

__global__ void k_final(const float* __restrict__ sacc,
                        const float* __restrict__ b2,
                        float* __restrict__ out) {
    if (threadIdx.x == 0 && blockIdx.x == 0) {
        float s0 = sacc[0] + (float)N_NODES * b2[0];
        float s1 = sacc[1] + (float)N_NODES * b2[1];
        float m = fmaxf(s0, s1);
        float e0 = __expf(s0 - m);
        float e1 = __expf(s1 - m);
        float inv = 1.0f / (e0 + e1);
        out[0] = e0 * inv;
        out[1] = e1 * inv;
    }
}

// ---------------- fallback path (R1 structure, ~8 MB ws) ----------------

__global__ __launch_bounds__(256) void k_init_fb(float* __restrict__ deg,
                                                 float* __restrict__ inagg,
                                                 float* __restrict__ outco,
                                                 float* __restrict__ sacc) {
    int i = blockIdx.x * blockDim.x + threadIdx.x;
    if (i < N_NODES) { deg[i] = 1.0f; inagg[i] = 0.0f; outco[i] = 0.0f; }
    if (i < 2) sacc[i] = 0.0f;
}

__global__ __launch_bounds__(256) void k_deg_fb(const int4* __restrict__ dst4,
                                                const float4* __restrict__ w4,
                                                float* __restrict__ deg) {
    int i = blockIdx.x * blockDim.x + threadIdx.x;
    int4 d = dst4[i]; float4 w = w4[i];
    atomicAdd(&deg[d.x], w.x); atomicAdd(&deg[d.y], w.y);
    atomicAdd(&deg[d.z], w.z); atomicAdd(&deg[d.w], w.w);
}

__global__ __launch_bounds__(256) void k_dis_fb(float* __restrict__ degdis,
                                                const float* __restrict__ x,
                                                float* __restrict__ y) {
    int i = blockIdx.x * blockDim.x + threadIdx.x;
    if (i < N_NODES) { float d = rsqrtf(degdis[i]); degdis[i] = d; y[i] = d * x[i]; }
}

__global__ __launch_bounds__(256) void k_edge2_fb(const int4* __restrict__ src4,
                                                  const int4* __restrict__ dst4,
                                                  const float4* __restrict__ w4,
                                                  const float* __restrict__ dis,
                                                  const float* __restrict__ y,
                                                  float* __restrict__ inagg,
                                                  float* __restrict__ outco) {
    int i = blockIdx.x * blockDim.x + threadIdx.x;
    int4 s = src4[i]; int4 d = dst4[i]; float4 w = w4[i];
    atomicAdd(&inagg[d.x], w.x * y[s.x]); atomicAdd(&inagg[d.y], w.y * y[s.y]);
    atomicAdd(&inagg[d.z], w.z * y[s.z]); atomicAdd(&inagg[d.w], w.w * y[s.w]);
    atomicAdd(&outco[s.x], w.x * dis[d.x]); atomicAdd(&outco[s.y], w.y * dis[d.y]);
    atomicAdd(&outco[s.z], w.z * dis[d.z]); atomicAdd(&outco[s.w], w.w * dis[d.w]);
}

__global__ __launch_bounds__(256) void k_node_fb(const float* __restrict__ dis,
                                                 const float* __restrict__ x,
                                                 const float* __restrict__ inagg,
                                                 const float* __restrict__ outco,
                                                 const float* __restrict__ W1,
                                                 const float* __restrict__ b1,
                                                 const float* __restrict__ W2,
                                                 float* __restrict__ sacc) {
    int i = blockIdx.x * blockDim.x + threadIdx.x;
    float c0 = 0.0f, c1 = 0.0f;
    if (i < N_NODES) {
        float dv = dis[i];
        float agg1 = dv * (inagg[i] + dv * x[i]);
        float coef = dv * outco[i] + dv * dv;
        float h0 = 0.0f, h1 = 0.0f;
#pragma unroll
        for (int j = 0; j < 16; ++j) {
            float a = fmaxf(fmaf(agg1, W1[j], b1[j]), 0.0f);
            h0 = fmaf(a, W2[2 * j + 0], h0);
            h1 = fmaf(a, W2[2 * j + 1], h1);
        }
        c0 = coef * h0; c1 = coef * h1;
    }
#pragma unroll
    for (int off = 32; off > 0; off >>= 1) {
        c0 += __shfl_down(c0, off, 64);
        c1 += __shfl_down(c1, off, 64);
    }
    __shared__ float red0[4], red1[4];
    int wave = threadIdx.x >> 6, lane = threadIdx.x & 63;
    if (lane == 0) { red0[wave] = c0; red1[wave] = c1; }
    __syncthreads();
    if (threadIdx.x == 0) {
        atomicAdd(&sacc[0], red0[0] + red0[1] + red0[2] + red0[3]);
        atomicAdd(&sacc[1], red1[0] + red1[1] + red1[2] + red1[3]);
    }
}

extern "C" void kernel_launch(void* const* d_in, const int* in_sizes, int n_in,
                              void* d_out, int out_size, void* d_ws, size_t ws_size,
                              hipStream_t stream) {
    const float* x  = (const float*)d_in[0];
    int*         ei = (int*)d_in[1];            // [2,E] int32 (row0 src, row1 dst)
    float*       ew = (float*)d_in[2];
    const float* W1 = (const float*)d_in[3];
    const float* b1 = (const float*)d_in[4];
    const float* W2 = (const float*)d_in[5];
    const float* b2 = (const float*)d_in[6];
    float* out = (float*)d_out;

    const int* src = ei;
    const int* dst = ei + N_EDGES;

    const int TB = 256;
    const int nodeBlocks = (N_NODES + TB - 1) / TB;

    // fast-path layout in ws
    char* base = (char*)d_ws;
    uint2*    A   = (uint2*)base;
    float*    y   = (float*)(base + 128000000);
    float*    dis = (float*)(base + 130000000);
    float2*   g2  = (float2*)(base + 132000000);
    unsigned* counts   = (unsigned*)(base + 136000000);
    unsigned* bases    = counts + (size_t)NB * NCHK;
    unsigned* offsets1 = bases + (size_t)NB * NCHK;
    unsigned* rowsum   = offsets1 + (NB + 1);
    unsigned* counts2  = rowsum + NB;
    unsigned* bases2   = counts2 + (size_t)NB * NB * SPB;
    unsigned* segbase  = bases2 + (size_t)NB * NB * SPB;
    float*    sacc     = (float*)(segbase + NSEG + 1);
    const size_t fastNeed = (size_t)((char*)(sacc + 2) - base) + 64;

    if (ws_size >= fastNeed) {
        // A2 (level-2 sorted) reuses edge_index (128 MB, consumed by scatter1);
        // deg/inagg staging reuses edge_weight (64 MB, consumed by scatter1)
        uint2* A2      = (uint2*)ei;
        float* staging = ew;           // NB*SPB*BSZ*4 = 32.2 MB <= 64 MB

        hipMemsetAsync(sacc, 0, 2 * sizeof(float), stream);

        k_count1<<<NCHK, TB, 0, stream>>>((const int4*)dst, counts);
        k_rowscan<<<NB, TB, 0, stream>>>(counts, bases, rowsum);
        k_bucketscan<<<1, 128, 0, stream>>>(rowsum, offsets1);
        k_scatter1<<<NCHK, TB, 0, stream>>>((const int4*)src, (const int4*)dst,
                                            (const float4*)ew, bases, offsets1, A);
        k_cd<<<NB * SPB, TB, 0, stream>>>(A, offsets1, counts2, staging);
        k_dis<<<nodeBlocks, TB, 0, stream>>>(staging, x, dis, y);
        k_scan2<<<NB, TB, 0, stream>>>(counts2, offsets1, bases2, segbase);
        k_scatter2<<<NB * SPB, TB, 0, stream>>>(A, offsets1, bases2, dis, A2);
        k_in<<<NB * SPB, TB, 0, stream>>>(A2, offsets1, y, staging);
        k_h<<<nodeBlocks, TB, 0, stream>>>(staging, dis, x, W1, b1, W2, g2, sacc);
        k_out<<<NB * SPB, TB, 0, stream>>>(A2, segbase, g2, sacc);
        k_final<<<1, 64, 0, stream>>>(sacc, b2, out);
    } else {
        float* ws     = (float*)d_ws;
        float* degdis = ws;
        float* yf     = ws + N_NODES;
        float* inaggf = ws + 2 * N_NODES;
        float* outcof = ws + 3 * N_NODES;
        float* saccf  = ws + 4 * N_NODES;
        const int edgeBlocks = (N_EDGES / 4) / TB;

        k_init_fb<<<nodeBlocks, TB, 0, stream>>>(degdis, inaggf, outcof, saccf);
        k_deg_fb<<<edgeBlocks, TB, 0, stream>>>((const int4*)dst, (const float4*)ew, degdis);
        k_dis_fb<<<nodeBlocks, TB, 0, stream>>>(degdis, x, yf);
        k_edge2_fb<<<edgeBlocks, TB, 0, stream>>>((const int4*)src, (const int4*)dst,
                                                  (const float4*)ew, degdis, yf, inaggf, outcof);
        k_node_fb<<<nodeBlocks, TB, 0, stream>>>(degdis, x, inaggf, outcof, W1, b1, W2, saccf);
        k_final<<<1, 64, 0, stream>>>(saccf, b2, out);
    }
}